// Round 1
// baseline (712.055 us; speedup 1.0000x reference)
//
#include <hip/hip_runtime.h>

#define N_TOK 8192
#define OUT_F 4096
#define IN_F  4096

typedef __bf16 bf16x8 __attribute__((ext_vector_type(8)));
typedef __bf16 bf16x4 __attribute__((ext_vector_type(4)));
typedef float  f32x4  __attribute__((ext_vector_type(4)));

#define AS1C(p) ((const __attribute__((address_space(1))) void*)(p))
#define AS3(p)  ((__attribute__((address_space(3))) void*)(p))

// ---------------------------------------------------------------------------
// Weight decode: bit-exact fp32 replication of the numpy/jax reference math,
// then RNE-round to bf16. NUM_BASEWEIGHTS == 2 is hard-wired.
//   Bs_k = sign(Cs_k) * B_k ;  R = |Cs0|*Bs0 + |Cs1|*Bs1
//   d0 = floor(R/Bs0); R2 = np.mod(R, Bs0); d1 = rint(R2/Bs1)
//   w = d0*Bs0 + d1*Bs1
// __fmul_rn/__fadd_rn/__fdiv_rn prevent fma contraction / fast-div so floor
// boundaries match the fp32 numpy reference exactly.
// ---------------------------------------------------------------------------
__device__ __forceinline__ float decode1(float c0, float c1, float b0, float b1) {
  float bs0 = (c0 < 0.0f) ? -b0 : b0;
  float bs1 = (c1 < 0.0f) ? -b1 : b1;
  float r  = __fadd_rn(__fmul_rn(fabsf(c0), bs0), __fmul_rn(fabsf(c1), bs1));
  float d0 = floorf(__fdiv_rn(r, bs0));
  float t  = fmodf(r, bs0);                       // truncated remainder
  if (t != 0.0f && ((t < 0.0f) != (bs0 < 0.0f)))  // numpy mod: sign follows divisor
    t = __fadd_rn(t, bs0);
  float d1 = rintf(__fdiv_rn(t, bs1));            // round half-to-even == np.round
  return __fadd_rn(__fmul_rn(d0, bs0), __fmul_rn(d1, bs1));
}

__global__ void decode_w_kernel(const float* __restrict__ Cs,
                                const float* __restrict__ Bm,
                                __bf16* __restrict__ Wb) {
  const long nw = (long)OUT_F * IN_F;             // 16,777,216 weights
  const long stride = (long)gridDim.x * blockDim.x;
  for (long t = blockIdx.x * (long)blockDim.x + threadIdx.x; t * 4 < nw; t += stride) {
    const long w = t * 4;                         // 4 weights / thread
    float4 c01 = *(const float4*)(Cs + 2 * w);    // (c0,c1) pairs, k fastest
    float4 c23 = *(const float4*)(Cs + 2 * w + 4);
    float4 b01 = *(const float4*)(Bm + 2 * w);
    float4 b23 = *(const float4*)(Bm + 2 * w + 4);
    bf16x4 o;
    o[0] = (__bf16)decode1(c01.x, c01.y, b01.x, b01.y);
    o[1] = (__bf16)decode1(c01.z, c01.w, b01.z, b01.w);
    o[2] = (__bf16)decode1(c23.x, c23.y, b23.x, b23.y);
    o[3] = (__bf16)decode1(c23.z, c23.w, b23.z, b23.w);
    *(bf16x4*)(Wb + w) = o;
  }
}

__global__ void convert_x_kernel(const float* __restrict__ X, __bf16* __restrict__ Xb) {
  const long n = (long)N_TOK * IN_F;
  const long stride = (long)gridDim.x * blockDim.x;
  for (long t = blockIdx.x * (long)blockDim.x + threadIdx.x; t * 8 < n; t += stride) {
    const long i = t * 8;
    float4 a = *(const float4*)(X + i);
    float4 b = *(const float4*)(X + i + 4);
    bf16x8 o;
    o[0] = (__bf16)a.x; o[1] = (__bf16)a.y; o[2] = (__bf16)a.z; o[3] = (__bf16)a.w;
    o[4] = (__bf16)b.x; o[5] = (__bf16)b.y; o[6] = (__bf16)b.z; o[7] = (__bf16)b.w;
    *(bf16x8*)(Xb + i) = o;
  }
}

// ---------------------------------------------------------------------------
// bf16 GEMM: out[M=8192][N=4096] = X[M][K] * W[N][K]^T + bias, fp32 out.
// m97 structure: 128x128 tile, BK=32, 256 thr = 4 waves (2x2), each wave a
// 64x64 subtile of 4x4 16x16x32 MFMA fragments. global_load_lds width 16.
// ---------------------------------------------------------------------------
#define BM 128
#define BN 128
#define BK 32

__global__ __launch_bounds__(256) void gemm_bias_kernel(
    const __bf16* __restrict__ X, const __bf16* __restrict__ W,
    const float* __restrict__ bias, float* __restrict__ out) {
  __shared__ __align__(16) char sA[BM * BK * 2];   // 8 KB, row-major [128][32] bf16
  __shared__ __align__(16) char sB[BN * BK * 2];   // 8 KB

  const int nN  = OUT_F / BN;                      // 32
  const int nwg = (N_TOK / BM) * nN;               // 2048 (divisible by 8)
  int bid = blockIdx.x;
  int swz = (bid & 7) * (nwg >> 3) + (bid >> 3);   // XCD-aware swizzle (bijective)
  int tm = swz / nN, tn = swz % nN;

  int tid  = threadIdx.x;
  int wave = tid >> 6, lane = tid & 63;
  int row0 = (wave >> 1) * 64, col0 = (wave & 1) * 64;

  const int off0 = wave * 1024 + lane * 16;        // byte offset within 8KB tile
  const int lr   = lane & 15;                      // fragment row (operand row)
  const int lkb  = (lane >> 4) << 4;               // k-group byte offset (8 bf16)

  f32x4 acc[4][4] = {};

  for (int k0 = 0; k0 < IN_F; k0 += BK) {
#pragma unroll
    for (int p = 0; p < 2; ++p) {
      int off = off0 + p * 4096;
      int row = off >> 6;                          // 64 B per LDS row
      int col = (off & 63) >> 1;                   // bf16 col within row
      const __bf16* ga = X + ((long)(tm * BM + row) * IN_F + k0 + col);
      const __bf16* gb = W + ((long)(tn * BN + row) * IN_F + k0 + col);
      // dest must be wave-uniform base; HW scatters lane*16
      __builtin_amdgcn_global_load_lds(AS1C(ga), AS3(sA + p * 4096 + wave * 1024), 16, 0, 0);
      __builtin_amdgcn_global_load_lds(AS1C(gb), AS3(sB + p * 4096 + wave * 1024), 16, 0, 0);
    }
    __syncthreads();

    bf16x8 af[4], bfr[4];
#pragma unroll
    for (int m = 0; m < 4; ++m)
      af[m] = *(const bf16x8*)(sA + (row0 + m * 16 + lr) * 64 + lkb);
#pragma unroll
    for (int n = 0; n < 4; ++n)
      bfr[n] = *(const bf16x8*)(sB + (col0 + n * 16 + lr) * 64 + lkb);

#pragma unroll
    for (int m = 0; m < 4; ++m)
#pragma unroll
      for (int n = 0; n < 4; ++n)
        acc[m][n] = __builtin_amdgcn_mfma_f32_16x16x32_bf16(af[m], bfr[n], acc[m][n], 0, 0, 0);
    __syncthreads();
  }

  // epilogue: C/D layout col=lane&15, row=(lane>>4)*4+reg  (m89-verified)
  const int lg = lane >> 4;
#pragma unroll
  for (int n = 0; n < 4; ++n) {
    int col = tn * BN + col0 + n * 16 + lr;
    float bv = bias[col];
#pragma unroll
    for (int m = 0; m < 4; ++m) {
      int row = tm * BM + row0 + m * 16 + lg * 4;
#pragma unroll
      for (int j = 0; j < 4; ++j)
        out[(long)(row + j) * OUT_F + col] = acc[m][n][j] + bv;
    }
  }
}

extern "C" void kernel_launch(void* const* d_in, const int* in_sizes, int n_in,
                              void* d_out, int out_size, void* d_ws, size_t ws_size,
                              hipStream_t stream) {
  (void)in_sizes; (void)n_in; (void)out_size; (void)ws_size;
  const float* x    = (const float*)d_in[0];
  const float* Cs   = (const float*)d_in[1];
  const float* Bm   = (const float*)d_in[2];
  const float* bias = (const float*)d_in[3];
  float* out = (float*)d_out;

  __bf16* xb = (__bf16*)d_ws;                                   // 67,108,864 B
  __bf16* wb = (__bf16*)((char*)d_ws + (size_t)N_TOK * IN_F * 2); // 33,554,432 B

  decode_w_kernel<<<2048, 256, 0, stream>>>(Cs, Bm, wb);
  convert_x_kernel<<<2048, 256, 0, stream>>>(x, xb);
  gemm_bias_kernel<<<2048, 256, 0, stream>>>(xb, wb, bias, out);
}